// Round 8
// baseline (120.237 us; speedup 1.0000x reference)
//
#include <hip/hip_runtime.h>
#include <cstddef>
#include <cstdint>

#define B_ 32
#define C_ 64
#define HW_ 16384
#define HW4_ 4096
#define PC_ 3
#define INV_N_ (1.0f/49152.0f)

typedef __attribute__((ext_vector_type(8))) short bf16x8;
typedef __attribute__((ext_vector_type(4))) float f32x4;

// ---- output layout (float indices) ----
#define OUT_DM_   ((size_t)B_*PC_*HW_)      // predicts first: 1572864
#define OUT_IDX_  (OUT_DM_ + (size_t)B_*64)
#define OUT_LOSS_ (OUT_IDX_ + B_)
#define OUT_DIST_ (OUT_LOSS_ + B_)

// ---- workspace layout (float indices) ----
#define SLOT_     2768
#define NUSED_    2755
#define REDU_OFF_ ((size_t)64)
#define PART_OFF_ (REDU_OFF_ + (size_t)B_*SLOT_)

// split f32 -> hi/lo bf16 (RNE each), hi+lo covers ~16 mantissa bits
__device__ __forceinline__ void split2(float x, short& hs, short& ls) {
    unsigned u = __float_as_uint(x);
    unsigned hr = (u + 0x7FFFu + ((u >> 16) & 1u)) >> 16;
    float hf = __uint_as_float(hr << 16);
    float r = x - hf;                       // exact
    unsigned v = __float_as_uint(r);
    unsigned lo = (v + 0x7FFFu + ((v >> 16) & 1u)) >> 16;
    hs = (short)hr; ls = (short)lo;
}

// 3-pass split-bf16 product accumulate: C += Ah*Bh + Ah*Bl + Al*Bh
__device__ __forceinline__ f32x4 mm3(bf16x8 ah, bf16x8 al, bf16x8 bh, bf16x8 bl, f32x4 c) {
    c = __builtin_amdgcn_mfma_f32_16x16x32_bf16(ah, bh, c, 0, 0, 0);
    c = __builtin_amdgcn_mfma_f32_16x16x32_bf16(ah, bl, c, 0, 0, 0);
    c = __builtin_amdgcn_mfma_f32_16x16x32_bf16(al, bh, c, 0, 0, 0);
    return c;
}

__device__ __forceinline__ void acc_dump(float* d, const f32x4* a) {
#pragma unroll
    for (int tt = 0; tt < 15; ++tt)
#pragma unroll
        for (int q = 0; q < 4; ++q) d[tt * 4 + q] = a[tt][q];
}
__device__ __forceinline__ void acc_add(f32x4* a, const float* d) {
#pragma unroll
    for (int tt = 0; tt < 15; ++tt)
#pragma unroll
        for (int q = 0; q < 4; ++q) a[tt][q] += d[tt * 4 + q];
}

// =====================================================================
// K1 (channel-phased): per (b, chunk of CPX px), 8 waves.
// Phase p (p=0..3) loads channel group p (16 ch x CPX px) as LONG
// contiguous bursts (CPX*4 bytes per channel stream, consumed in one
// phase), converts to bf16 hi/lo once, writes swizzled LDS planes.
// Wave w owns K-window px [w*CPX/8, +CPX/8); per phase computes the
// newly-available tiles: p0:{M00,v0,rr} p1:{M01,M11,v1}
// p2:{M02,M12,M22,v2} p3:{M03,M13,M23,M33,v3}. 8-wave tree reduce.
// =====================================================================
template<int CPX, int NCH>
__global__ __launch_bounds__(512, (CPX == 256 ? 4 : 2))
void k1_stats(const float* __restrict__ feat, const float* __restrict__ target,
              const float* __restrict__ pred, float* __restrict__ ws) {
    constexpr int J   = CPX / 256;     // 8-px granules per thread per channel
    constexpr int PX4 = CPX / 4;
    const int b = blockIdx.x / NCH, chunk = blockIdx.x % NCH;
    const int t = threadIdx.x;
    const int wv = t >> 6, lane = t & 63, lr = lane & 15, lg = lane >> 4;
    const int ch16 = t >> 5;           // 0..15 (staging channel within group)
    const int p32  = t & 31;
    const int rpc  = t >> 5;           // pc for r-staging threads (t<96)

    __shared__ __align__(16) short smem[2 * 64 * CPX + 6 * CPX];
    short* sfH = smem;                 // [64][CPX]
    short* sfL = smem + 64 * CPX;
    short* srH = smem + 128 * CPX;     // [3][CPX]
    short* srL = smem + 128 * CPX + 3 * CPX;

    f32x4 acc[15];
#pragma unroll
    for (int i = 0; i < 15; ++i) acc[i] = (f32x4){0.f, 0.f, 0.f, 0.f};

    const float4* feat4 = (const float4*)feat;
    const float4* pred4 = (const float4*)pred;
    const float4* targ4 = (const float4*)target;
    const size_t fb = (size_t)(b * 64 + ch16) * HW4_ + (size_t)chunk * PX4 + p32 * 2;
    const size_t rb = ((size_t)b * 3 + rpc) * HW4_ + (size_t)chunk * PX4 + p32 * 2;

    float4 sA[2 * J], sB[2 * J], rp[2 * J], rt[2 * J];

    auto LOADF = [&](float4* S, int g) {
#pragma unroll
        for (int j = 0; j < J; ++j) {
            S[2*j]   = feat4[fb + (size_t)g * 16 * HW4_ + j * 64];
            S[2*j+1] = feat4[fb + (size_t)g * 16 * HW4_ + j * 64 + 1];
        }
    };
    auto WRITEF = [&](const float4* S, int g) {
        const int ch = g * 16 + ch16;
#pragma unroll
        for (int j = 0; j < J; ++j) {
            const float fx[8] = {S[2*j].x, S[2*j].y, S[2*j].z, S[2*j].w,
                                 S[2*j+1].x, S[2*j+1].y, S[2*j+1].z, S[2*j+1].w};
            bf16x8 hv, lv;
#pragma unroll
            for (int i = 0; i < 8; ++i) { short h, l; split2(fx[i], h, l); hv[i] = h; lv[i] = l; }
            const int so = (p32 * 8 + j * 256) ^ ((ch16 & 7) << 3);
            *(bf16x8*)&sfH[ch * CPX + so] = hv;
            *(bf16x8*)&sfL[ch * CPX + so] = lv;
        }
    };
    auto LOADR = [&]() {
        if (t < 96) {
#pragma unroll
            for (int j = 0; j < J; ++j) {
                rp[2*j]   = pred4[rb + j * 64];
                rp[2*j+1] = pred4[rb + j * 64 + 1];
                rt[2*j]   = targ4[rb + j * 64];
                rt[2*j+1] = targ4[rb + j * 64 + 1];
            }
        }
    };
    auto WRITER = [&]() {
        if (t < 96) {
#pragma unroll
            for (int j = 0; j < J; ++j) {
                const float fx[8] = {rp[2*j].x - rt[2*j].x, rp[2*j].y - rt[2*j].y,
                                     rp[2*j].z - rt[2*j].z, rp[2*j].w - rt[2*j].w,
                                     rp[2*j+1].x - rt[2*j+1].x, rp[2*j+1].y - rt[2*j+1].y,
                                     rp[2*j+1].z - rt[2*j+1].z, rp[2*j+1].w - rt[2*j+1].w};
                bf16x8 hv, lv;
#pragma unroll
                for (int i = 0; i < 8; ++i) { short h, l; split2(fx[i], h, l); hv[i] = h; lv[i] = l; }
                const int so = (p32 * 8 + j * 256) ^ (rpc << 3);
                *(bf16x8*)&srH[rpc * CPX + so] = hv;
                *(bf16x8*)&srL[rpc * CPX + so] = lv;
            }
        }
    };
    auto FR = [&](int g, int ks, bf16x8& h, bf16x8& l) {
        const int ko = wv * (CPX / 8) + ks * 32 + lg * 8;
        const int off = ko ^ ((lr & 7) << 3);
        const int ch = g * 16 + lr;
        h = *(const bf16x8*)&sfH[ch * CPX + off];
        l = *(const bf16x8*)&sfL[ch * CPX + off];
    };
    auto RR = [&](int ks, bf16x8& h, bf16x8& l) {
        h = (bf16x8){0,0,0,0,0,0,0,0}; l = h;
        if (lr < 3) {
            const int ko = wv * (CPX / 8) + ks * 32 + lg * 8;
            const int off = ko ^ (lr << 3);
            h = *(const bf16x8*)&srH[lr * CPX + off];
            l = *(const bf16x8*)&srL[lr * CPX + off];
        }
    };

    // ---- prologue: G0+r and G1 in flight; write G0+r ----
    LOADF(sA, 0); LOADR(); LOADF(sB, 1);
    WRITEF(sA, 0); WRITER();
    __syncthreads();
    LOADF(sA, 2);                       // 2 phases of flight
    // ---- phase 0 ----
#pragma unroll
    for (int ks = 0; ks < J; ++ks) {
        bf16x8 f0h, f0l, rh, rl2;
        FR(0, ks, f0h, f0l); RR(ks, rh, rl2);
        acc[0]  = mm3(f0h, f0l, f0h, f0l, acc[0]);    // M00
        acc[10] = mm3(rh, rl2, f0h, f0l, acc[10]);    // v0
        acc[14] = mm3(rh, rl2, rh, rl2, acc[14]);     // rr
    }
    WRITEF(sB, 1);
    __syncthreads();
    LOADF(sB, 3);
    // ---- phase 1 ----
#pragma unroll
    for (int ks = 0; ks < J; ++ks) {
        bf16x8 f0h, f0l, f1h, f1l, rh, rl2;
        FR(0, ks, f0h, f0l); FR(1, ks, f1h, f1l); RR(ks, rh, rl2);
        acc[1]  = mm3(f0h, f0l, f1h, f1l, acc[1]);    // M01
        acc[4]  = mm3(f1h, f1l, f1h, f1l, acc[4]);    // M11
        acc[11] = mm3(rh, rl2, f1h, f1l, acc[11]);    // v1
    }
    WRITEF(sA, 2);
    __syncthreads();
    // ---- phase 2 ----
#pragma unroll
    for (int ks = 0; ks < J; ++ks) {
        bf16x8 f0h, f0l, f1h, f1l, f2h, f2l, rh, rl2;
        FR(0, ks, f0h, f0l); FR(1, ks, f1h, f1l); FR(2, ks, f2h, f2l); RR(ks, rh, rl2);
        acc[2]  = mm3(f0h, f0l, f2h, f2l, acc[2]);    // M02
        acc[5]  = mm3(f1h, f1l, f2h, f2l, acc[5]);    // M12
        acc[7]  = mm3(f2h, f2l, f2h, f2l, acc[7]);    // M22
        acc[12] = mm3(rh, rl2, f2h, f2l, acc[12]);    // v2
    }
    WRITEF(sB, 3);
    __syncthreads();
    // ---- phase 3 ----
#pragma unroll
    for (int ks = 0; ks < J; ++ks) {
        bf16x8 f0h, f0l, f1h, f1l, f2h, f2l, f3h, f3l, rh, rl2;
        FR(0, ks, f0h, f0l); FR(1, ks, f1h, f1l); FR(2, ks, f2h, f2l);
        FR(3, ks, f3h, f3l); RR(ks, rh, rl2);
        acc[3]  = mm3(f0h, f0l, f3h, f3l, acc[3]);    // M03
        acc[6]  = mm3(f1h, f1l, f3h, f3l, acc[6]);    // M13
        acc[8]  = mm3(f2h, f2l, f3h, f3l, acc[8]);    // M23
        acc[9]  = mm3(f3h, f3l, f3h, f3l, acc[9]);    // M33
        acc[13] = mm3(rh, rl2, f3h, f3l, acc[13]);    // v3
    }
    __syncthreads();

    // ---- 8-wave deterministic tree reduce (alias smem as float) ----
    float* red = (float*)smem;
    float* b0p = red + (size_t)lane * 69;
    float* b1p = red + (size_t)64 * 69 + (size_t)lane * 69;
    if (wv == 4) acc_dump(b0p, acc);
    if (wv == 5) acc_dump(b1p, acc);
    __syncthreads();
    if (wv == 0) acc_add(acc, b0p);
    if (wv == 1) acc_add(acc, b1p);
    __syncthreads();
    if (wv == 6) acc_dump(b0p, acc);
    if (wv == 7) acc_dump(b1p, acc);
    __syncthreads();
    if (wv == 2) acc_add(acc, b0p);
    if (wv == 3) acc_add(acc, b1p);
    __syncthreads();
    if (wv == 2) acc_dump(b0p, acc);
    if (wv == 3) acc_dump(b1p, acc);
    __syncthreads();
    if (wv == 0) acc_add(acc, b0p);
    if (wv == 1) acc_add(acc, b1p);
    __syncthreads();
    if (wv == 1) acc_dump(b0p, acc);
    __syncthreads();

    if (wv == 0) {
        acc_add(acc, b0p);
        float* P = ws + PART_OFF_ + (size_t)blockIdx.x * SLOT_;
        // tile-major upper tiles; elem e=q*64+lane <-> (r16=(lane>>4)*4+q, c16=lane&15)
#pragma unroll
        for (int tt = 0; tt < 10; ++tt)
#pragma unroll
            for (int q = 0; q < 4; ++q)
                P[tt * 256 + q * 64 + lane] = acc[tt][q];
        if (lg == 0) {
#pragma unroll
            for (int g = 0; g < 4; ++g) {
                P[2560 + 0 * 64 + g * 16 + lr] = acc[10 + g][0];
                P[2560 + 1 * 64 + g * 16 + lr] = acc[10 + g][1];
                P[2560 + 2 * 64 + g * 16 + lr] = acc[10 + g][2];
            }
        }
        if (lane == 0) P[2752] = acc[14][0];
        if (lane == 1) P[2753] = acc[14][1];
        if (lane == 2) P[2754] = acc[14][2];
    }
}

// =====================================================================
// K2a: grid-wide reduce of NCH partial slots per b (352 blocks)
// =====================================================================
template<int NCH>
__global__ __launch_bounds__(256)
void k2a_reduce(float* __restrict__ ws) {
    const int b = blockIdx.x / 11, blk = blockIdx.x % 11;
    const int pos = blk * 256 + threadIdx.x;
    if (pos >= NUSED_) return;
    const float* P = ws + PART_OFF_ + (size_t)b * NCH * SLOT_ + pos;
    float s = 0.f;
#pragma unroll 4
    for (int c = 0; c < NCH; ++c) s += P[(size_t)c * SLOT_];
    ws[REDU_OFF_ + (size_t)b * SLOT_ + pos] = s;
}

// =====================================================================
// K2b: rebuild M (mirror), dist_k = (w^T M w + 2 w.v + rsq)/N; argmin.
// =====================================================================
__global__ __launch_bounds__(256)
void k2b_dist(const float* __restrict__ weight, float* __restrict__ ws,
              float* __restrict__ dout) {
    const int b = blockIdx.x, t = threadIdx.x;
    __shared__ __align__(16) float Ml[64][64];
    __shared__ __align__(16) float vl[192];
    __shared__ float red[3][64];
    __shared__ float rl;

    const float* R = ws + REDU_OFF_ + (size_t)b * SLOT_;
    const int TI[10] = {0,0,0,0,1,1,1,2,2,3};
    const int TJ[10] = {0,1,2,3,1,2,3,2,3,3};
    {
        const int q = t >> 6, lg2 = (t >> 4) & 3, lr2 = t & 15;
        const int r16 = lg2 * 4 + q, c16 = lr2;
#pragma unroll
        for (int r = 0; r < 10; ++r) {
            const int gi = TI[r], gj = TJ[r];
            const float val = R[r * 256 + t];
            Ml[gi * 16 + r16][gj * 16 + c16] = val;
            if (gi != gj) Ml[gj * 16 + c16][gi * 16 + r16] = val;
        }
    }
    if (t < 192) vl[t] = R[2560 + t];
    if (t == 0) rl = R[2752] + R[2753] + R[2754];
    __syncthreads();

    if (t < 192) {
        const int k = t & 63, pc = t >> 6;
        const float4* wr = (const float4*)(weight + (size_t)(3 * k + pc) * 64);
        float4 w[16];
#pragma unroll
        for (int j = 0; j < 16; ++j) w[j] = wr[j];
        float s = 0.f;
#pragma unroll 2
        for (int i4 = 0; i4 < 16; ++i4) {
            const float wi[4] = {w[i4].x, w[i4].y, w[i4].z, w[i4].w};
#pragma unroll
            for (int ii = 0; ii < 4; ++ii) {
                const int i = i4 * 4 + ii;
                const float4* Mr = (const float4*)&Ml[i][0];
                float4 ya = make_float4(0.f, 0.f, 0.f, 0.f);
#pragma unroll
                for (int j = 0; j < 16; ++j) {
                    ya.x += Mr[j].x * w[j].x; ya.y += Mr[j].y * w[j].y;
                    ya.z += Mr[j].z * w[j].z; ya.w += Mr[j].w * w[j].w;
                }
                s += wi[ii] * (ya.x + ya.y + ya.z + ya.w);
            }
        }
        const float4* vl4 = (const float4*)&vl[pc * 64];
        float4 sv = make_float4(0.f, 0.f, 0.f, 0.f);
#pragma unroll
        for (int j = 0; j < 16; ++j) {
            sv.x += vl4[j].x * w[j].x; sv.y += vl4[j].y * w[j].y;
            sv.z += vl4[j].z * w[j].z; sv.w += vl4[j].w * w[j].w;
        }
        red[pc][k] = s + 2.f * (sv.x + sv.y + sv.z + sv.w);
    }
    __syncthreads();
    if (t < 64) {
        float d = (red[0][t] + red[1][t] + red[2][t] + rl) * INV_N_;
        dout[OUT_DM_ + (size_t)b * 64 + t] = d;
        int idx = t;
#pragma unroll
        for (int off = 32; off >= 1; off >>= 1) {
            const float od = __shfl_xor(d, off);
            const int   oi = __shfl_xor(idx, off);
            if (od < d || (od == d && oi < idx)) { d = od; idx = oi; }
        }
        if (t == 0) {
            ((int*)ws)[b] = idx;
            dout[OUT_IDX_  + b] = (float)idx;
            dout[OUT_LOSS_ + b] = d;   // loss == distances mathematically
            dout[OUT_DIST_ + b] = d;
        }
    }
}

// =====================================================================
// K4: winning candidate only. 2048 blocks; 4 waves split the channel dim.
// =====================================================================
__global__ __launch_bounds__(256)
void k4_pred(const float* __restrict__ feat, const float* __restrict__ predl,
             const float* __restrict__ weight, const float* __restrict__ ws,
             float* __restrict__ dout) {
    const int b = blockIdx.x >> 6, sb = blockIdx.x & 63;
    const int t = threadIdx.x, lane = t & 63, wv = t >> 6;
    __shared__ float wl[PC_][64];
    __shared__ __align__(16) float4 red[3][PC_][64];
    const int kbest = ((const int*)ws)[b];
    if (t < 192) wl[t >> 6][t & 63] = weight[(size_t)(kbest * 3 + (t >> 6)) * 64 + (t & 63)];
    __syncthreads();
    const int hw4 = sb * 64 + lane;
    const float4* f4 = (const float4*)feat;
    const size_t base4 = (size_t)b * C_ * HW4_ + hw4;
    float4 a0 = {0,0,0,0}, a1 = {0,0,0,0}, a2 = {0,0,0,0};
#pragma unroll
    for (int i = 0; i < 16; ++i) {
        const int c = wv * 16 + i;
        const float4 f = f4[base4 + (size_t)c * HW4_];
        const float w0 = wl[0][c], w1 = wl[1][c], w2 = wl[2][c];
        a0.x += f.x*w0; a0.y += f.y*w0; a0.z += f.z*w0; a0.w += f.w*w0;
        a1.x += f.x*w1; a1.y += f.y*w1; a1.z += f.z*w1; a1.w += f.w*w1;
        a2.x += f.x*w2; a2.y += f.y*w2; a2.z += f.z*w2; a2.w += f.w*w2;
    }
    const float4* p4 = (const float4*)predl;
    const size_t ob = (size_t)b * PC_ * HW4_ + hw4;
    float4 pl0, pl1, pl2;
    if (wv == 0) { pl0 = p4[ob]; pl1 = p4[ob + 4096]; pl2 = p4[ob + 8192]; }
    else { red[wv-1][0][lane] = a0; red[wv-1][1][lane] = a1; red[wv-1][2][lane] = a2; }
    __syncthreads();
    if (wv == 0) {
#pragma unroll
        for (int w = 0; w < 3; ++w) {
            const float4 x0 = red[w][0][lane], x1 = red[w][1][lane], x2 = red[w][2][lane];
            a0.x += x0.x; a0.y += x0.y; a0.z += x0.z; a0.w += x0.w;
            a1.x += x1.x; a1.y += x1.y; a1.z += x1.z; a1.w += x1.w;
            a2.x += x2.x; a2.y += x2.y; a2.z += x2.z; a2.w += x2.w;
        }
        a0.x += pl0.x; a0.y += pl0.y; a0.z += pl0.z; a0.w += pl0.w;
        a1.x += pl1.x; a1.y += pl1.y; a1.z += pl1.z; a1.w += pl1.w;
        a2.x += pl2.x; a2.y += pl2.y; a2.z += pl2.z; a2.w += pl2.w;
        float4* o4 = (float4*)dout;
        o4[ob]        = a0;
        o4[ob + 4096] = a1;
        o4[ob + 8192] = a2;
    }
}

extern "C" void kernel_launch(void* const* d_in, const int* in_sizes, int n_in,
                              void* d_out, int out_size, void* d_ws, size_t ws_size,
                              hipStream_t stream) {
    const float* feat   = (const float*)d_in[0];
    const float* target = (const float*)d_in[1];
    const float* predl  = (const float*)d_in[2];
    const float* weight = (const float*)d_in[3];
    float* out = (float*)d_out;
    float* wsf = (float*)d_ws;

    const size_t need256 = (PART_OFF_ + (size_t)2048 * SLOT_) * sizeof(float);
    if (ws_size >= need256) {
        hipLaunchKernelGGL((k1_stats<256, 64>), dim3(B_ * 64), dim3(512), 0, stream,
                           feat, target, predl, wsf);
        hipLaunchKernelGGL((k2a_reduce<64>), dim3(B_ * 11), dim3(256), 0, stream, wsf);
    } else {
        hipLaunchKernelGGL((k1_stats<512, 32>), dim3(B_ * 32), dim3(512), 0, stream,
                           feat, target, predl, wsf);
        hipLaunchKernelGGL((k2a_reduce<32>), dim3(B_ * 11), dim3(256), 0, stream, wsf);
    }
    hipLaunchKernelGGL(k2b_dist, dim3(B_), dim3(256), 0, stream,
                       weight, wsf, out);
    hipLaunchKernelGGL(k4_pred, dim3(B_ * 64), dim3(256), 0, stream,
                       feat, predl, weight, wsf, out);
}

// Round 9
// 103.606 us; speedup vs baseline: 1.1605x; 1.1605x over previous
//
#include <hip/hip_runtime.h>
#include <cstddef>
#include <cstdint>

#define B_ 32
#define C_ 64
#define HW_ 16384
#define HW4_ 4096
#define PC_ 3
#define NCHK_ 32
#define INV_N_ (1.0f/49152.0f)

typedef __attribute__((ext_vector_type(8))) short bf16x8;
typedef __attribute__((ext_vector_type(4))) short s16x4;
typedef __attribute__((ext_vector_type(4))) float f32x4;

// ---- output layout (float indices) ----
#define OUT_DM_   ((size_t)B_*PC_*HW_)      // predicts first: 1572864
#define OUT_IDX_  (OUT_DM_ + (size_t)B_*64)
#define OUT_LOSS_ (OUT_IDX_ + B_)
#define OUT_DIST_ (OUT_LOSS_ + B_)

// ---- workspace layout (float indices) ----
#define SLOT_     2768
#define NUSED_    2755
#define REDU_OFF_ ((size_t)64)
#define PART_OFF_ (REDU_OFF_ + (size_t)B_*SLOT_)
// total: (64 + (32 + 1024)*2768)*4 B ~= 11.7 MB (ws proven >= 22.9 MB in R8)

// split f32 -> hi/lo bf16 (RNE each), hi+lo covers ~16 mantissa bits
__device__ __forceinline__ void split2(float x, short& hs, short& ls) {
    unsigned u = __float_as_uint(x);
    unsigned hr = (u + 0x7FFFu + ((u >> 16) & 1u)) >> 16;
    float hf = __uint_as_float(hr << 16);
    float r = x - hf;                       // exact
    unsigned v = __float_as_uint(r);
    unsigned lo = (v + 0x7FFFu + ((v >> 16) & 1u)) >> 16;
    hs = (short)hr; ls = (short)lo;
}

// 3-pass split-bf16 product accumulate: C += Ah*Bh + Ah*Bl + Al*Bh
__device__ __forceinline__ f32x4 mm3(bf16x8 ah, bf16x8 al, bf16x8 bh, bf16x8 bl, f32x4 c) {
    c = __builtin_amdgcn_mfma_f32_16x16x32_bf16(ah, bh, c, 0, 0, 0);
    c = __builtin_amdgcn_mfma_f32_16x16x32_bf16(ah, bl, c, 0, 0, 0);
    c = __builtin_amdgcn_mfma_f32_16x16x32_bf16(al, bh, c, 0, 0, 0);
    return c;
}

// =====================================================================
// K1: per (b, chunk of 512 px) processed as 4 subchunks of 128 px.
// ALL loads for a subchunk issued upfront (8 independent float4/thread
// + r), k4-style; next subchunk's loads in flight under current compute.
// Split-bf16 at staging into XOR-swizzled hi/lo LDS planes; wave->tile
// partition (R7, no cross-wave reduce): w0:{M00,M01,M11,v0}
// w1:{M22,M23,M33,v2} w2:{M02,M12,v1} w3:{M03,M13,v3,rr}.
// 1024 blocks, 4 blocks/CU.
// =====================================================================
__global__ __launch_bounds__(256, 4)
void k1_stats(const float* __restrict__ feat, const float* __restrict__ target,
              const float* __restrict__ pred, float* __restrict__ ws) {
    const int b = blockIdx.x >> 5, chunk = blockIdx.x & 31;
    const int t = threadIdx.x, wv = t >> 6, lane = t & 63;
    const int lr = lane & 15, lg = lane >> 4;
    const int ch = t >> 2, q = t & 3;          // staging: 4 threads per channel
    const int rpc = t >> 5, rm = t & 31;       // r staging (t<96)

    __shared__ __align__(16) short fH[64][128];   // 16 KB
    __shared__ __align__(16) short fL[64][128];   // 16 KB
    __shared__ __align__(16) short rH[3][128];
    __shared__ __align__(16) short rL[3][128];

    f32x4 acc[4];
#pragma unroll
    for (int i = 0; i < 4; ++i) acc[i] = (f32x4){0.f, 0.f, 0.f, 0.f};

    const float4* feat4 = (const float4*)feat;
    const float4* pred4 = (const float4*)pred;
    const float4* targ4 = (const float4*)target;
    const size_t fb = (size_t)(b * 64 + ch) * HW4_ + (size_t)chunk * 128 + q;
    const size_t rb = ((size_t)b * 3 + rpc) * HW4_ + (size_t)chunk * 128 + rm;

    float4 sf[8];
    float4 rp = {0,0,0,0}, rt = {0,0,0,0};

    auto LOAD = [&](int sc) {                    // all independent, issued at once
#pragma unroll
        for (int j = 0; j < 8; ++j) sf[j] = feat4[fb + sc * 32 + 4 * j];
        if (t < 96) { rp = pred4[rb + sc * 32]; rt = targ4[rb + sc * 32]; }
    };
    auto WRITE = [&]() {
#pragma unroll
        for (int j = 0; j < 8; ++j) {
            const int m = q + 4 * j;
            const int so = (m * 4) ^ ((ch & 7) << 3);
            const float fx[4] = {sf[j].x, sf[j].y, sf[j].z, sf[j].w};
            s16x4 hv, lv;
#pragma unroll
            for (int i = 0; i < 4; ++i) { short h, l; split2(fx[i], h, l); hv[i] = h; lv[i] = l; }
            *(s16x4*)&fH[ch][so] = hv;
            *(s16x4*)&fL[ch][so] = lv;
        }
        if (t < 96) {
            const int so = (rm * 4) ^ (rpc << 3);
            const float fx[4] = {rp.x - rt.x, rp.y - rt.y, rp.z - rt.z, rp.w - rt.w};
            s16x4 hv, lv;
#pragma unroll
            for (int i = 0; i < 4; ++i) { short h, l; split2(fx[i], h, l); hv[i] = h; lv[i] = l; }
            *(s16x4*)&rH[rpc][so] = hv;
            *(s16x4*)&rL[rpc][so] = lv;
        }
    };
    auto FR = [&](int g, int ks, bf16x8& h, bf16x8& l) {
        const int off = (ks * 32 + lg * 8) ^ ((lr & 7) << 3);
        h = *(const bf16x8*)&fH[g * 16 + lr][off];
        l = *(const bf16x8*)&fL[g * 16 + lr][off];
    };
    auto RR = [&](int ks, bf16x8& h, bf16x8& l) {
        h = (bf16x8){0,0,0,0,0,0,0,0}; l = h;
        if (lr < 3) {
            const int off = (ks * 32 + lg * 8) ^ (lr << 3);
            h = *(const bf16x8*)&rH[lr][off];
            l = *(const bf16x8*)&rL[lr][off];
        }
    };
    auto COMPUTE = [&]() {
#pragma unroll
        for (int ks = 0; ks < 4; ++ks) {
            if (wv == 0) {
                bf16x8 a0h,a0l,a1h,a1l,rh,rl2;
                FR(0, ks, a0h, a0l); FR(1, ks, a1h, a1l); RR(ks, rh, rl2);
                acc[0] = mm3(a0h,a0l,a0h,a0l,acc[0]);   // M00
                acc[1] = mm3(a0h,a0l,a1h,a1l,acc[1]);   // M01
                acc[2] = mm3(a1h,a1l,a1h,a1l,acc[2]);   // M11
                acc[3] = mm3(rh,rl2,a0h,a0l,acc[3]);    // v0
            } else if (wv == 1) {
                bf16x8 a2h,a2l,a3h,a3l,rh,rl2;
                FR(2, ks, a2h, a2l); FR(3, ks, a3h, a3l); RR(ks, rh, rl2);
                acc[0] = mm3(a2h,a2l,a2h,a2l,acc[0]);   // M22
                acc[1] = mm3(a2h,a2l,a3h,a3l,acc[1]);   // M23
                acc[2] = mm3(a3h,a3l,a3h,a3l,acc[2]);   // M33
                acc[3] = mm3(rh,rl2,a2h,a2l,acc[3]);    // v2
            } else if (wv == 2) {
                bf16x8 a0h,a0l,a1h,a1l,a2h,a2l,rh,rl2;
                FR(0, ks, a0h, a0l); FR(1, ks, a1h, a1l); FR(2, ks, a2h, a2l); RR(ks, rh, rl2);
                acc[0] = mm3(a0h,a0l,a2h,a2l,acc[0]);   // M02
                acc[1] = mm3(a1h,a1l,a2h,a2l,acc[1]);   // M12
                acc[2] = mm3(rh,rl2,a1h,a1l,acc[2]);    // v1
            } else {
                bf16x8 a0h,a0l,a1h,a1l,a3h,a3l,rh,rl2;
                FR(0, ks, a0h, a0l); FR(1, ks, a1h, a1l); FR(3, ks, a3h, a3l); RR(ks, rh, rl2);
                acc[0] = mm3(a0h,a0l,a3h,a3l,acc[0]);   // M03
                acc[1] = mm3(a1h,a1l,a3h,a3l,acc[1]);   // M13
                acc[2] = mm3(rh,rl2,a3h,a3l,acc[2]);    // v3
                acc[3] = mm3(rh,rl2,rh,rl2,acc[3]);     // rr
            }
        }
    };

    // ---- pipeline: next subchunk's loads always in flight under compute ----
    LOAD(0);
    WRITE();                    // waits sub0 loads (only ones outstanding)
    LOAD(1);                    // sub1 in flight across barrier+compute
    __syncthreads();
    COMPUTE();                  // sub0
    __syncthreads();
    WRITE();                    // waits sub1 loads (had full compute to land)
    LOAD(2);
    __syncthreads();
    COMPUTE();                  // sub1
    __syncthreads();
    WRITE();
    LOAD(3);
    __syncthreads();
    COMPUTE();                  // sub2
    __syncthreads();
    WRITE();
    __syncthreads();
    COMPUTE();                  // sub3

    // ---- epilogue: wave-private coalesced stores (tile-major) ----
    // tile order tt: (0,0),(0,1),(0,2),(0,3),(1,1),(1,2),(1,3),(2,2),(2,3),(3,3)
    float* P = ws + PART_OFF_ + (size_t)blockIdx.x * SLOT_;
    if (wv == 0) {
#pragma unroll
        for (int qq = 0; qq < 4; ++qq) {
            P[0 * 256 + qq * 64 + lane] = acc[0][qq];   // M00
            P[1 * 256 + qq * 64 + lane] = acc[1][qq];   // M01
            P[4 * 256 + qq * 64 + lane] = acc[2][qq];   // M11
        }
        if (lg == 0) {
            P[2560 + 0 * 64 + 0 + lr] = acc[3][0];      // v0
            P[2560 + 1 * 64 + 0 + lr] = acc[3][1];
            P[2560 + 2 * 64 + 0 + lr] = acc[3][2];
        }
    } else if (wv == 1) {
#pragma unroll
        for (int qq = 0; qq < 4; ++qq) {
            P[7 * 256 + qq * 64 + lane] = acc[0][qq];   // M22
            P[8 * 256 + qq * 64 + lane] = acc[1][qq];   // M23
            P[9 * 256 + qq * 64 + lane] = acc[2][qq];   // M33
        }
        if (lg == 0) {
            P[2560 + 0 * 64 + 32 + lr] = acc[3][0];     // v2
            P[2560 + 1 * 64 + 32 + lr] = acc[3][1];
            P[2560 + 2 * 64 + 32 + lr] = acc[3][2];
        }
    } else if (wv == 2) {
#pragma unroll
        for (int qq = 0; qq < 4; ++qq) {
            P[2 * 256 + qq * 64 + lane] = acc[0][qq];   // M02
            P[5 * 256 + qq * 64 + lane] = acc[1][qq];   // M12
        }
        if (lg == 0) {
            P[2560 + 0 * 64 + 16 + lr] = acc[2][0];     // v1
            P[2560 + 1 * 64 + 16 + lr] = acc[2][1];
            P[2560 + 2 * 64 + 16 + lr] = acc[2][2];
        }
    } else {
#pragma unroll
        for (int qq = 0; qq < 4; ++qq) {
            P[3 * 256 + qq * 64 + lane] = acc[0][qq];   // M03
            P[6 * 256 + qq * 64 + lane] = acc[1][qq];   // M13
        }
        if (lg == 0) {
            P[2560 + 0 * 64 + 48 + lr] = acc[2][0];     // v3
            P[2560 + 1 * 64 + 48 + lr] = acc[2][1];
            P[2560 + 2 * 64 + 48 + lr] = acc[2][2];
        }
        if (lane == 0) P[2752] = acc[3][0];             // rr diag
        if (lane == 1) P[2753] = acc[3][1];
        if (lane == 2) P[2754] = acc[3][2];
    }
}

// =====================================================================
// K2a: reduce 32 partial slots per b (352 blocks); 4 accumulators break
// the serial latency chain, full unroll keeps many loads in flight.
// =====================================================================
__global__ __launch_bounds__(256)
void k2a_reduce(float* __restrict__ ws) {
    const int b = blockIdx.x / 11, blk = blockIdx.x % 11;
    const int pos = blk * 256 + threadIdx.x;
    if (pos >= NUSED_) return;
    const float* P = ws + PART_OFF_ + (size_t)b * NCHK_ * SLOT_ + pos;
    float s0 = 0.f, s1 = 0.f, s2 = 0.f, s3 = 0.f;
#pragma unroll
    for (int c = 0; c < NCHK_; c += 4) {
        s0 += P[(size_t)c * SLOT_];
        s1 += P[(size_t)(c + 1) * SLOT_];
        s2 += P[(size_t)(c + 2) * SLOT_];
        s3 += P[(size_t)(c + 3) * SLOT_];
    }
    ws[REDU_OFF_ + (size_t)b * SLOT_ + pos] = (s0 + s1) + (s2 + s3);
}

// =====================================================================
// K2b: rebuild M (mirror), dist_k = (w^T M w + 2 w.v + rsq)/N; argmin.
// =====================================================================
__global__ __launch_bounds__(256)
void k2b_dist(const float* __restrict__ weight, float* __restrict__ ws,
              float* __restrict__ dout) {
    const int b = blockIdx.x, t = threadIdx.x;
    __shared__ __align__(16) float Ml[64][64];
    __shared__ __align__(16) float vl[192];
    __shared__ float red[3][64];
    __shared__ float rl;

    const float* R = ws + REDU_OFF_ + (size_t)b * SLOT_;
    const int TI[10] = {0,0,0,0,1,1,1,2,2,3};
    const int TJ[10] = {0,1,2,3,1,2,3,2,3,3};
    {
        const int q = t >> 6, lg2 = (t >> 4) & 3, lr2 = t & 15;
        const int r16 = lg2 * 4 + q, c16 = lr2;
#pragma unroll
        for (int r = 0; r < 10; ++r) {
            const int gi = TI[r], gj = TJ[r];
            const float val = R[r * 256 + t];
            Ml[gi * 16 + r16][gj * 16 + c16] = val;
            if (gi != gj) Ml[gj * 16 + c16][gi * 16 + r16] = val;
        }
    }
    if (t < 192) vl[t] = R[2560 + t];
    if (t == 0) rl = R[2752] + R[2753] + R[2754];
    __syncthreads();

    if (t < 192) {
        const int k = t & 63, pc = t >> 6;
        const float4* wr = (const float4*)(weight + (size_t)(3 * k + pc) * 64);
        float4 w[16];
#pragma unroll
        for (int j = 0; j < 16; ++j) w[j] = wr[j];
        float s = 0.f;
#pragma unroll 2
        for (int i4 = 0; i4 < 16; ++i4) {
            const float wi[4] = {w[i4].x, w[i4].y, w[i4].z, w[i4].w};
#pragma unroll
            for (int ii = 0; ii < 4; ++ii) {
                const int i = i4 * 4 + ii;
                const float4* Mr = (const float4*)&Ml[i][0];
                float4 ya = make_float4(0.f, 0.f, 0.f, 0.f);
#pragma unroll
                for (int j = 0; j < 16; ++j) {
                    ya.x += Mr[j].x * w[j].x; ya.y += Mr[j].y * w[j].y;
                    ya.z += Mr[j].z * w[j].z; ya.w += Mr[j].w * w[j].w;
                }
                s += wi[ii] * (ya.x + ya.y + ya.z + ya.w);
            }
        }
        const float4* vl4 = (const float4*)&vl[pc * 64];
        float4 sv = make_float4(0.f, 0.f, 0.f, 0.f);
#pragma unroll
        for (int j = 0; j < 16; ++j) {
            sv.x += vl4[j].x * w[j].x; sv.y += vl4[j].y * w[j].y;
            sv.z += vl4[j].z * w[j].z; sv.w += vl4[j].w * w[j].w;
        }
        red[pc][k] = s + 2.f * (sv.x + sv.y + sv.z + sv.w);
    }
    __syncthreads();
    if (t < 64) {
        float d = (red[0][t] + red[1][t] + red[2][t] + rl) * INV_N_;
        dout[OUT_DM_ + (size_t)b * 64 + t] = d;
        int idx = t;
#pragma unroll
        for (int off = 32; off >= 1; off >>= 1) {
            const float od = __shfl_xor(d, off);
            const int   oi = __shfl_xor(idx, off);
            if (od < d || (od == d && oi < idx)) { d = od; idx = oi; }
        }
        if (t == 0) {
            ((int*)ws)[b] = idx;
            dout[OUT_IDX_  + b] = (float)idx;
            dout[OUT_LOSS_ + b] = d;   // loss == distances mathematically
            dout[OUT_DIST_ + b] = d;
        }
    }
}

// =====================================================================
// K4: winning candidate only. 2048 blocks; 4 waves split the channel dim.
// =====================================================================
__global__ __launch_bounds__(256)
void k4_pred(const float* __restrict__ feat, const float* __restrict__ predl,
             const float* __restrict__ weight, const float* __restrict__ ws,
             float* __restrict__ dout) {
    const int b = blockIdx.x >> 6, sb = blockIdx.x & 63;
    const int t = threadIdx.x, lane = t & 63, wv = t >> 6;
    __shared__ float wl[PC_][64];
    __shared__ __align__(16) float4 red[3][PC_][64];
    const int kbest = ((const int*)ws)[b];
    if (t < 192) wl[t >> 6][t & 63] = weight[(size_t)(kbest * 3 + (t >> 6)) * 64 + (t & 63)];
    __syncthreads();
    const int hw4 = sb * 64 + lane;
    const float4* f4 = (const float4*)feat;
    const size_t base4 = (size_t)b * C_ * HW4_ + hw4;
    float4 a0 = {0,0,0,0}, a1 = {0,0,0,0}, a2 = {0,0,0,0};
#pragma unroll
    for (int i = 0; i < 16; ++i) {
        const int c = wv * 16 + i;
        const float4 f = f4[base4 + (size_t)c * HW4_];
        const float w0 = wl[0][c], w1 = wl[1][c], w2 = wl[2][c];
        a0.x += f.x*w0; a0.y += f.y*w0; a0.z += f.z*w0; a0.w += f.w*w0;
        a1.x += f.x*w1; a1.y += f.y*w1; a1.z += f.z*w1; a1.w += f.w*w1;
        a2.x += f.x*w2; a2.y += f.y*w2; a2.z += f.z*w2; a2.w += f.w*w2;
    }
    const float4* p4 = (const float4*)predl;
    const size_t ob = (size_t)b * PC_ * HW4_ + hw4;
    float4 pl0, pl1, pl2;
    if (wv == 0) { pl0 = p4[ob]; pl1 = p4[ob + 4096]; pl2 = p4[ob + 8192]; }
    else { red[wv-1][0][lane] = a0; red[wv-1][1][lane] = a1; red[wv-1][2][lane] = a2; }
    __syncthreads();
    if (wv == 0) {
#pragma unroll
        for (int w = 0; w < 3; ++w) {
            const float4 x0 = red[w][0][lane], x1 = red[w][1][lane], x2 = red[w][2][lane];
            a0.x += x0.x; a0.y += x0.y; a0.z += x0.z; a0.w += x0.w;
            a1.x += x1.x; a1.y += x1.y; a1.z += x1.z; a1.w += x1.w;
            a2.x += x2.x; a2.y += x2.y; a2.z += x2.z; a2.w += x2.w;
        }
        a0.x += pl0.x; a0.y += pl0.y; a0.z += pl0.z; a0.w += pl0.w;
        a1.x += pl1.x; a1.y += pl1.y; a1.z += pl1.z; a1.w += pl1.w;
        a2.x += pl2.x; a2.y += pl2.y; a2.z += pl2.z; a2.w += pl2.w;
        float4* o4 = (float4*)dout;
        o4[ob]        = a0;
        o4[ob + 4096] = a1;
        o4[ob + 8192] = a2;
    }
}

extern "C" void kernel_launch(void* const* d_in, const int* in_sizes, int n_in,
                              void* d_out, int out_size, void* d_ws, size_t ws_size,
                              hipStream_t stream) {
    const float* feat   = (const float*)d_in[0];
    const float* target = (const float*)d_in[1];
    const float* predl  = (const float*)d_in[2];
    const float* weight = (const float*)d_in[3];
    float* out = (float*)d_out;
    float* wsf = (float*)d_ws;
    (void)ws_size;

    hipLaunchKernelGGL(k1_stats, dim3(B_ * NCHK_), dim3(256), 0, stream,
                       feat, target, predl, wsf);
    hipLaunchKernelGGL(k2a_reduce, dim3(B_ * 11), dim3(256), 0, stream, wsf);
    hipLaunchKernelGGL(k2b_dist, dim3(B_), dim3(256), 0, stream,
                       weight, wsf, out);
    hipLaunchKernelGGL(k4_pred, dim3(B_ * 64), dim3(256), 0, stream,
                       feat, predl, weight, wsf, out);
}